// Round 15
// baseline (507.915 us; speedup 1.0000x reference)
//
#include <hip/hip_runtime.h>
#include <stdint.h>

// ---------------------------------------------------------------------------
// MultiHeadAttention: out = softmax(mask((X Wq^T)(X Wk^T)^T * E^-0.5)) (X Wv^T) Wo^T + bo
// N=4, L=2048, E=2048, H=16, D=128.  bf16 MFMA GEMMs, f32 softmax.
// R14 -> R15: attn KVB 64 -> 128 (single-buffered, 64KB LDS, 2 blocks/CU).
// Tile count 17 -> 9: halves per-tile fixed costs (2 syncs, stage round,
// vmax/rsum shfl rounds, defer-max check) at +6% MFMA (tail 1152 vs 1088
// key-slots). V-transpose covers 128 j via two half-chunks (vj0, vj0+64;
// bit6 doesn't interact with the (d&7)<<3 XOR -> per-instruction bank
// pattern identical to R6's floor). PV kk extends to 0..3, pa built from
// u[kk*2],u[kk*2+1] (keys kk*32..+31 -- derivation generalizes verbatim).
// GEMM & pre-stages R9-verbatim (196us QKV / ~96us outproj measured).
// Workspace (128MB + 64KB):
//   [0,64KB)      idx (int[4][2048]), cnts (int[8])
//   [64KB,+32MB)  Wqb,Wkb,Wvb,Wob (bf16, 8MB each)
//   [+32MB)       qp  (Q proj, pre-scaled; attn output aliases this)
//   [+32MB)       kp  (query bf16 staging, then compacted K proj)
//   [+32MB)       vp  (compacted V proj)
//   d_out (64MB)  xk (lo 32MB) + xv (hi 32MB) staging; overwritten by final GEMM.
// ---------------------------------------------------------------------------

typedef __bf16 bf16;
typedef __bf16 bf16x2 __attribute__((ext_vector_type(2)));
typedef __bf16 bf16x4 __attribute__((ext_vector_type(4)));
typedef __bf16 bf16x8 __attribute__((ext_vector_type(8)));
typedef float  f32x4  __attribute__((ext_vector_type(4)));
typedef uint32_t u32x4 __attribute__((ext_vector_type(4)));

#define MFMA16(a, b, c) __builtin_amdgcn_mfma_f32_16x16x32_bf16(a, b, c, 0, 0, 0)

__device__ __forceinline__ void gload_lds16(const void* g, void* s) {
  __builtin_amdgcn_global_load_lds(
      (const __attribute__((address_space(1))) void*)g,
      (__attribute__((address_space(3))) void*)s, 16, 0, 0);
}

__device__ __forceinline__ uint32_t pkbf(float a, float b) {
  return __builtin_bit_cast(uint32_t, (bf16x2){(bf16)a, (bf16)b});
}

// raw v_exp_f32 (exp2); avoids the OCML correctly-rounded polynomial
__device__ __forceinline__ float fexp2(float x) {
  return __builtin_amdgcn_exp2f(x);
}

// ---------------------------------------------------------------------------
// 8 EE-sized f32->bf16 conversions in one launch: y<4 weights, y>=4 query 1/4s.
// ---------------------------------------------------------------------------
__global__ __launch_bounds__(256) void cvt8_bf16(const float* __restrict__ s0,
                                                 const float* __restrict__ s1,
                                                 const float* __restrict__ s2,
                                                 const float* __restrict__ s3,
                                                 const float* __restrict__ q,
                                                 bf16* __restrict__ d0,
                                                 bf16* __restrict__ d1,
                                                 bf16* __restrict__ d2,
                                                 bf16* __restrict__ d3,
                                                 bf16* __restrict__ dq,
                                                 long EE) {
  int y = blockIdx.y;
  const float* src;
  bf16* dst;
  if (y < 4) {
    src = y == 0 ? s0 : y == 1 ? s1 : y == 2 ? s2 : s3;
    dst = y == 0 ? d0 : y == 1 ? d1 : y == 2 ? d2 : d3;
  } else {
    src = q + (long)(y - 4) * EE;
    dst = dq + (long)(y - 4) * EE;
  }
  long i = ((long)blockIdx.x * 256 + threadIdx.x) * 4;
  f32x4 f = *(const f32x4*)(src + i);
  bf16x4 h = { (bf16)f.x, (bf16)f.y, (bf16)f.z, (bf16)f.w };
  *(bf16x4*)(dst + i) = h;
}

// ---------------------------------------------------------------------------
// Fused K+V gather through compacted idx, f32->bf16; skips rows >= cntp128.
// ---------------------------------------------------------------------------
__global__ __launch_bounds__(256) void gather2_cvt(const float* __restrict__ ks,
                                                   const float* __restrict__ vs,
                                                   bf16* __restrict__ kd,
                                                   bf16* __restrict__ vd,
                                                   const int* __restrict__ idx,
                                                   const int* __restrict__ cnts) {
  long i = (long)blockIdx.x * 256 + threadIdx.x;  // unit of 8 elements
  int row = (int)(i >> 8);
  int u = (int)(i & 255);
  int n = row >> 11, p = row & 2047;
  if (p >= cnts[4 + n]) return;                   // pad rows never consumed
  long srow = ((long)n << 11) + idx[(n << 11) + p];
  long so = srow * 2048 + u * 8;
  long dof = (long)row * 2048 + u * 8;
  {
    f32x4 a = *(const f32x4*)(ks + so);
    f32x4 b = *(const f32x4*)(ks + so + 4);
    bf16x8 h = { (bf16)a.x, (bf16)a.y, (bf16)a.z, (bf16)a.w,
                 (bf16)b.x, (bf16)b.y, (bf16)b.z, (bf16)b.w };
    *(bf16x8*)(kd + dof) = h;
  }
  {
    f32x4 a = *(const f32x4*)(vs + so);
    f32x4 b = *(const f32x4*)(vs + so + 4);
    bf16x8 h = { (bf16)a.x, (bf16)a.y, (bf16)a.z, (bf16)a.w,
                 (bf16)b.x, (bf16)b.y, (bf16)b.z, (bf16)b.w };
    *(bf16x8*)(vd + dof) = h;
  }
}

// ---------------------------------------------------------------------------
// Per-n compaction of mask==1 indices. grid = 4 x 256.
// ---------------------------------------------------------------------------
__global__ __launch_bounds__(256) void mask_compact(const int* __restrict__ mask,
                                                    int* __restrict__ idx,
                                                    int* __restrict__ cnts) {
  const int n = blockIdx.x;
  const int t = threadIdx.x, l = t & 63, w = t >> 6;
  const int* m = mask + n * 2048;
  __shared__ int wtot[4];
  int f[8], tt = 0;
  const int base = t * 8;
#pragma unroll
  for (int i = 0; i < 8; ++i) { f[i] = (m[base + i] != 0); tt += f[i]; }
  int sc = tt;
#pragma unroll
  for (int d = 1; d < 64; d <<= 1) {
    int v = __shfl_up(sc, d);
    if (l >= d) sc += v;
  }
  if (l == 63) wtot[w] = sc;
  __syncthreads();
  int woff = 0;
#pragma unroll
  for (int i = 0; i < 4; ++i) if (i < w) woff += wtot[i];
  int off = woff + sc - tt;
#pragma unroll
  for (int i = 0; i < 8; ++i)
    if (f[i]) { idx[n * 2048 + off] = base + i; ++off; }
  int total = wtot[0] + wtot[1] + wtot[2] + wtot[3];
  for (int p = total + t; p < 2048; p += 256) idx[n * 2048 + p] = 2047;
  if (t == 0) { cnts[n] = total; cnts[4 + n] = (total + 127) & ~127; }
}

// ---------------------------------------------------------------------------
// 256x256 GEMM, counted-vmcnt double-buffered pipeline (R9 verbatim —
// measured best: 196us QKV / ~96us outproj). QKV mode: blockIdx.z selects
// {Q: scale no-exit, K/V: exit no-scale} at runtime (uniform branches).
// ---------------------------------------------------------------------------
template <int QKV, int OUT_F32, int ADD_BIAS>
__global__ __launch_bounds__(512, 2) void gemm256(const bf16* __restrict__ A0,
                                                  const bf16* __restrict__ A1,
                                                  const bf16* __restrict__ A2,
                                                  const bf16* __restrict__ B0,
                                                  const bf16* __restrict__ B1,
                                                  const bf16* __restrict__ B2,
                                                  void* __restrict__ C0,
                                                  void* __restrict__ C1,
                                                  void* __restrict__ C2,
                                                  const float* __restrict__ bias,
                                                  const int* __restrict__ cnts) {
  constexpr int K = 2048, LDC = 2048, NT = 32;
  constexpr int TILE = 256 * 64;
  __shared__ bf16 S[2 * 2 * TILE];
  const int t = threadIdx.x;
  const int l = t & 63, w = t >> 6;
  const int wr = w >> 2, wc = w & 3;
  const int l15 = l & 15, l4 = l >> 4;

  const int z = blockIdx.z;
  const bf16* A = z == 0 ? A0 : z == 1 ? A1 : A2;
  const bf16* B = z == 0 ? B0 : z == 1 ? B1 : B2;
  void* Cout = z == 0 ? C0 : z == 1 ? C1 : C2;

  const int Mb = ((blockIdx.x & 7) << 2) + (blockIdx.x >> 3);
  const long tm = (long)Mb * 256;
  const long tn = (long)blockIdx.y * 256;

  if constexpr (QKV) {
    if (z) {  // K/V projections: skip blocks past compacted count
      int n = (int)(tm >> 11);
      if ((int)(tm & 2047) >= cnts[4 + n]) return;
    }
  }

  const bf16* Ab = A + tm * K;
  const bf16* Bb = B + tn * K;

  auto stage = [&](int T, int p) {
    bf16* sA = S + p * 2 * TILE;
    bf16* sB = sA + TILE;
    const bf16* Ak = Ab + T * 64;
    const bf16* Bk = Bb + T * 64;
#pragma unroll
    for (int i = 0; i < 4; ++i) {
      int u = i * 512 + t;
      int row = u >> 3, slot = u & 7;
      int ss = slot ^ (row & 7);
      gload_lds16(Ak + (long)row * K + ss * 8, sA + u * 8);
    }
#pragma unroll
    for (int i = 0; i < 4; ++i) {
      int u = i * 512 + t;
      int row = u >> 3, slot = u & 7;
      int ss = slot ^ (row & 7);
      gload_lds16(Bk + (long)row * K + ss * 8, sB + u * 8);
    }
  };

  f32x4 acc[8][4];
#pragma unroll
  for (int i = 0; i < 8; ++i)
#pragma unroll
    for (int j = 0; j < 4; ++j) acc[i][j] = (f32x4){0.f, 0.f, 0.f, 0.f};

  stage(0, 0);

  for (int T = 0; T < NT; ++T) {
    const int p = T & 1;
    const bf16* sA = S + p * 2 * TILE;
    const bf16* sB = sA + TILE;

    asm volatile("" ::: "memory");
    __builtin_amdgcn_s_barrier();
    asm volatile("" ::: "memory");
    if (T + 1 < NT) {
      stage(T + 1, p ^ 1);
      asm volatile("s_waitcnt vmcnt(8)" ::: "memory");
    } else {
      asm volatile("s_waitcnt vmcnt(0)" ::: "memory");
    }
    __builtin_amdgcn_s_barrier();
    asm volatile("" ::: "memory");

#pragma unroll
    for (int kk = 0; kk < 2; ++kk) {
      bf16x8 af[8], bf[4];
#pragma unroll
      for (int mi = 0; mi < 8; ++mi) {
        int row = wr * 128 + mi * 16 + l15;
        int slot = (kk * 4 + l4) ^ (row & 7);
        af[mi] = *(const bf16x8*)(sA + row * 64 + slot * 8);
      }
#pragma unroll
      for (int ni = 0; ni < 4; ++ni) {
        int row = wc * 64 + ni * 16 + l15;
        int slot = (kk * 4 + l4) ^ (row & 7);
        bf[ni] = *(const bf16x8*)(sB + row * 64 + slot * 8);
      }
      __builtin_amdgcn_s_setprio(1);
#pragma unroll
      for (int mi = 0; mi < 8; ++mi)
#pragma unroll
        for (int ni = 0; ni < 4; ++ni)
          acc[mi][ni] = MFMA16(af[mi], bf[ni], acc[mi][ni]);
      __builtin_amdgcn_s_setprio(0);
    }
  }

  // Q projection pre-scales logits into log2 domain (E^-0.5 * log2e)
  const float sc = (QKV && blockIdx.z == 0) ? 0.031879357f : 1.0f;
#pragma unroll
  for (int mi = 0; mi < 8; ++mi) {
#pragma unroll
    for (int ni = 0; ni < 4; ++ni) {
      long col = tn + wc * 64 + ni * 16 + l15;
      long row = tm + wr * 128 + mi * 16 + l4 * 4;
#pragma unroll
      for (int r = 0; r < 4; ++r) {
        float v = acc[mi][ni][r];
        if constexpr (QKV) v *= sc;
        if constexpr (OUT_F32) {
          if constexpr (ADD_BIAS) v += bias[col];
          ((float*)Cout)[(row + r) * (long)LDC + col] = v;
        } else {
          ((bf16*)Cout)[(row + r) * (long)LDC + col] = (bf16)v;
        }
      }
    }
  }
}

// ---------------------------------------------------------------------------
// Flash attention over COMPACTED keys. 1024 blocks x 512 threads (8 waves x
// 16 q-rows), XCD-swizzled decode. KVB=128, single-buffered (64KB LDS ->
// 2 blocks/CU, 4 waves/SIMD): 9 tiles instead of 17 halves per-tile fixed
// costs. V-transpose via two half-chunks (vj0, vj0+64); R6 bank-floor
// mapping per chunk. Q pre-scaled (log2 domain); native v_exp_f32;
// defer-max THR=11.5; T5 setprio. launch_bounds (512,4): cap 128 VGPR
// (do NOT force 8 -- R13 lesson).
// ---------------------------------------------------------------------------
__global__ __launch_bounds__(512, 4) void attn_fwd(const bf16* __restrict__ Qp,
                                                   const bf16* __restrict__ Kp,
                                                   const bf16* __restrict__ Vp,
                                                   const int* __restrict__ cnts,
                                                   bf16* __restrict__ Op) {
  constexpr int L = 2048, E = 2048, KVB = 128;
  __shared__ bf16 Kt[KVB * 128];      // [j][16 slots of 8], swizzled  32KB
  __shared__ bf16 VT[128 * KVB];      // [d][j], swizzled              32KB
  const int t = threadIdx.x, l = t & 63, w = t >> 6;
  const int l15 = l & 15, l4 = l >> 4;

  const int b = blockIdx.x;
  const int slot = ((b & 7) << 7) + (b >> 3);
  const int q0 = (slot & 15) << 7;
  const int y = slot >> 4;
  const int n = y >> 4, h = y & 15;
  const int wq = w * 16;

  const bf16* Qb = Qp + ((long)n * L + q0) * E + h * 128;
  const bf16* Kb = Kp + (long)n * L * E + h * 128;
  const bf16* Vb = Vp + (long)n * L * E + h * 128;
  const int cnt = cnts[n];
  const int ntk = (cnt + 127) >> 7;   // tiles of 128 keys

  bf16x8 qf[4];
#pragma unroll
  for (int kk = 0; kk < 4; ++kk)
    qf[kk] = *(const bf16x8*)(Qb + (long)(wq + l15) * E + kk * 32 + l4 * 8);

  f32x4 o[8];
#pragma unroll
  for (int ni = 0; ni < 8; ++ni) o[ni] = (f32x4){0.f, 0.f, 0.f, 0.f};
  float mreg = -1e20f, lreg = 0.f;

  // V-transpose mapping (R6 floor per chunk; two chunks cover 128 j)
  const int vj0 = ((l15 & 1) + 2 * l4 + 8 * (w & 1)) * 4;
  const int vd0 = ((l15 >> 1) + 8 * (w >> 1)) * 4;

  for (int ti = 0; ti < ntk; ++ti) {
    const int kv = ti << 7;

    // ---- stage K (async gload_lds, 4 rounds) + V (reg transpose, 2 chunks)
#pragma unroll
    for (int i = 0; i < 4; ++i) {
      int u = i * 512 + t;
      int row = u >> 4, sl = u & 15;
      gload_lds16(Kb + (long)(kv + row) * E + ((sl ^ (row & 7)) * 8),
                  &Kt[u * 8]);
    }
#pragma unroll
    for (int hh = 0; hh < 2; ++hh) {
      const int vjh = vj0 + hh * 64;
      bf16x4 vr[4];
#pragma unroll
      for (int r = 0; r < 4; ++r)
        vr[r] = *(const bf16x4*)(Vb + (long)(kv + vjh + r) * E + vd0);
#pragma unroll
      for (int i = 0; i < 4; ++i) {
        int d = vd0 + i;
        bf16x4 pk = { vr[0][i], vr[1][i], vr[2][i], vr[3][i] };
        *(bf16x4*)(&VT[d * KVB + (vjh ^ ((d & 7) << 3))]) = pk;
      }
    }
    __syncthreads();   // drains vmcnt/lgkm: Kt + VT ready for all waves

    // ---- S^T = K Q^T  (rows j 0..127, cols q); S pre-scaled, log2 domain
    f32x4 s[8];
#pragma unroll
    for (int ni = 0; ni < 8; ++ni) s[ni] = (f32x4){0.f, 0.f, 0.f, 0.f};
#pragma unroll
    for (int kk = 0; kk < 4; ++kk) {
      bf16x8 kf[8];
#pragma unroll
      for (int ni = 0; ni < 8; ++ni) {
        int row = ni * 16 + l15;
        int sl = (kk * 4 + l4) ^ (row & 7);
        kf[ni] = *(const bf16x8*)(&Kt[row * 128 + sl * 8]);
      }
      __builtin_amdgcn_s_setprio(1);
#pragma unroll
      for (int ni = 0; ni < 8; ++ni)
        s[ni] = MFMA16(kf[ni], qf[kk], s[ni]);
      __builtin_amdgcn_s_setprio(0);
    }

    // ---- tail mask only (j >= cnt -> -1e20); non-tail tiles: nothing
    if (kv + KVB > cnt) {
#pragma unroll
      for (int ni = 0; ni < 8; ++ni)
#pragma unroll
        for (int r = 0; r < 4; ++r) {
          int j = kv + ni * 16 + l4 * 4 + r;
          s[ni][r] = (j < cnt) ? s[ni][r] : -1e20f;
        }
    }

    // ---- online softmax (exp2 domain, native v_exp); defer-max THR=11.5
    float vmax = -1e20f;
#pragma unroll
    for (int ni = 0; ni < 8; ++ni)
#pragma unroll
      for (int r = 0; r < 4; ++r) vmax = fmaxf(vmax, s[ni][r]);
    vmax = fmaxf(vmax, __shfl_xor(vmax, 16));
    vmax = fmaxf(vmax, __shfl_xor(vmax, 32));
    bool nd = vmax > mreg + 11.5f;
    float corr = nd ? fexp2(mreg - vmax) : 1.0f;
    float mn = nd ? vmax : mreg;
    mreg = mn;
    float rsum = 0.f;
    uint32_t u[8][2];
#pragma unroll
    for (int ni = 0; ni < 8; ++ni) {
      float p0 = fexp2(s[ni][0] - mn);
      float p1 = fexp2(s[ni][1] - mn);
      float p2 = fexp2(s[ni][2] - mn);
      float p3 = fexp2(s[ni][3] - mn);
      rsum += (p0 + p1) + (p2 + p3);
      u[ni][0] = pkbf(p0, p1);
      u[ni][1] = pkbf(p2, p3);
    }
    rsum += __shfl_xor(rsum, 16);
    rsum += __shfl_xor(rsum, 32);
    lreg = lreg * corr + rsum;
    if (__any(nd)) {               // rare: rescale o (rows q = wq + l4*4 + r)
#pragma unroll
      for (int r = 0; r < 4; ++r) {
        float cr = __shfl(corr, l4 * 20 + r);
#pragma unroll
        for (int ni = 0; ni < 8; ++ni) o[ni][r] *= cr;
      }
    }

    // ---- P redistribute (in-register) + PV over 4 key-slots of 32
    const int srcA = l15 + ((l & 16) << 1);
    const int srcB = srcA + 16;
    const bool e5 = (l4 >> 1) != 0;
#pragma unroll
    for (int kk = 0; kk < 4; ++kk) {
      uint32_t a0 = (uint32_t)__shfl((int)u[kk * 2][0], srcA);
      uint32_t a1 = (uint32_t)__shfl((int)u[kk * 2][1], srcA);
      uint32_t a2 = (uint32_t)__shfl((int)u[kk * 2][0], srcB);
      uint32_t a3 = (uint32_t)__shfl((int)u[kk * 2][1], srcB);
      uint32_t b0 = (uint32_t)__shfl((int)u[kk * 2 + 1][0], srcA);
      uint32_t b1 = (uint32_t)__shfl((int)u[kk * 2 + 1][1], srcA);
      uint32_t b2 = (uint32_t)__shfl((int)u[kk * 2 + 1][0], srcB);
      uint32_t b3 = (uint32_t)__shfl((int)u[kk * 2 + 1][1], srcB);
      u32x4 pw = { e5 ? b0 : a0, e5 ? b1 : a1, e5 ? b2 : a2, e5 ? b3 : a3 };
      bf16x8 pa = __builtin_bit_cast(bf16x8, pw);
      bf16x8 vb[8];
#pragma unroll
      for (int ni = 0; ni < 8; ++ni) {
        int d = ni * 16 + l15;
        int col = (kk * 32 + l4 * 8) ^ ((d & 7) << 3);
        vb[ni] = *(const bf16x8*)(&VT[d * KVB + col]);
      }
      __builtin_amdgcn_s_setprio(1);
#pragma unroll
      for (int ni = 0; ni < 8; ++ni)
        o[ni] = MFMA16(pa, vb[ni], o[ni]);
      __builtin_amdgcn_s_setprio(0);
    }

    __syncthreads();   // all waves done reading Kt/VT before next overwrite
  }

  // ---- epilogue (rows q = wq + l4*4 + r; 1/l held at lane l15=q)
  float inv = 1.f / lreg;
#pragma unroll
  for (int r = 0; r < 4; ++r) {
    float iv = __shfl(inv, l4 * 20 + r);
    long grow = (long)n * L + q0 + wq + l4 * 4 + r;
#pragma unroll
    for (int ni = 0; ni < 8; ++ni)
      Op[grow * E + h * 128 + ni * 16 + l15] = (bf16)(o[ni][r] * iv);
  }
}

// ---------------------------------------------------------------------------
extern "C" void kernel_launch(void* const* d_in, const int* in_sizes, int n_in,
                              void* d_out, int out_size, void* d_ws, size_t ws_size,
                              hipStream_t stream) {
  (void)in_sizes; (void)n_in; (void)out_size; (void)ws_size;
  const float* query = (const float*)d_in[0];
  const float* keys  = (const float*)d_in[1];
  const float* values= (const float*)d_in[2];
  const int*   mask  = (const int*)d_in[3];
  const float* Wq = (const float*)d_in[4];
  const float* Wk = (const float*)d_in[5];
  const float* Wv = (const float*)d_in[6];
  const float* Wo = (const float*)d_in[7];
  const float* bo = (const float*)d_in[8];
  float* out = (float*)d_out;

  const int N = 4, L = 2048, E = 2048;
  const int M = N * L;  // 8192
  const long EE = (long)E * E;
  const long ME = (long)M * E;

  int*  idx  = (int*)d_ws;
  int*  cnts = idx + N * 2048;
  bf16* Wqb  = (bf16*)((char*)d_ws + 65536);
  bf16* Wkb  = Wqb + EE;
  bf16* Wvb  = Wkb + EE;
  bf16* Wob  = Wvb + EE;
  bf16* qp   = Wob + EE;
  bf16* kp   = qp + ME;    // query staging first, then K projection
  bf16* vp   = kp + ME;
  bf16* xq   = kp;                         // bf16 query staging (dead @ K-GEMM)
  bf16* xk   = (bf16*)d_out;               // gathered keys   (lo 32MB of d_out)
  bf16* xv   = (bf16*)d_out + ME;          // gathered values (hi 32MB of d_out)

  const int cbw = (int)(EE / 4 / 256);     // 4096
  const int gbl = (int)(ME / 8 / 256);     // 8192
  dim3 ggqkv(32, 8, 3);
  dim3 gg(32, 8, 1);

  mask_compact<<<4, 256, 0, stream>>>(mask, idx, cnts);
  cvt8_bf16<<<dim3(cbw, 8), 256, 0, stream>>>(Wq, Wk, Wv, Wo, query,
                                              Wqb, Wkb, Wvb, Wob, xq, EE);
  gather2_cvt<<<gbl, 256, 0, stream>>>(keys, values, xk, xv, idx, cnts);

  // Q+K+V projections in ONE launch (z=0: Q pre-scaled; z=1: K; z=2: V)
  gemm256<1, 0, 0><<<ggqkv, 512, 0, stream>>>(xq, xk, xv, Wqb, Wkb, Wvb,
                                              qp, kp, vp, nullptr, cnts);
  // attention over compacted keys (output aliases qp)
  attn_fwd<<<1024, 512, 0, stream>>>(qp, kp, vp, cnts, qp);
  // output projection + bias (overwrites all of d_out incl. xk/xv)
  gemm256<0, 1, 1><<<gg, 512, 0, stream>>>(qp, qp, qp, Wob, Wob, Wob,
                                           out, out, out, bo, cnts);
}

// Round 16
// 426.788 us; speedup vs baseline: 1.1901x; 1.1901x over previous
//
#include <hip/hip_runtime.h>
#include <stdint.h>

// ---------------------------------------------------------------------------
// MultiHeadAttention: out = softmax(mask((X Wq^T)(X Wk^T)^T * E^-0.5)) (X Wv^T) Wo^T + bo
// N=4, L=2048, E=2048, H=16, D=128.  bf16 MFMA GEMMs, f32 softmax.
// R15 -> R16: REVERT to R14 verbatim (measured 429.0us, session best).
// R15's KVB=128 doubled attn live state past the 64-VGPR budget -> scratch
// spills (WRITE 348MB, attn 230us). KVB=64 single-buffered is the verified
// sweet spot: state fits 64 VGPR, 8 waves/SIMD natural, no spills.
// Session ledger: GEMM = R9 2-barrier counted-vmcnt 256^2 (3 schedule
// rewrites regressed); attn = swapped-QK^T + in-reg P + exp2-native +
// pre-scaled Q + defer-max + R6 V-mapping; mask compaction ~2x; 6 launches.
// Workspace (128MB + 64KB):
//   [0,64KB)      idx (int[4][2048]), cnts (int[8])
//   [64KB,+32MB)  Wqb,Wkb,Wvb,Wob (bf16, 8MB each)
//   [+32MB)       qp  (Q proj, pre-scaled; attn output aliases this)
//   [+32MB)       kp  (query bf16 staging, then compacted K proj)
//   [+32MB)       vp  (compacted V proj)
//   d_out (64MB)  xk (lo 32MB) + xv (hi 32MB) staging; overwritten by final GEMM.
// ---------------------------------------------------------------------------

typedef __bf16 bf16;
typedef __bf16 bf16x2 __attribute__((ext_vector_type(2)));
typedef __bf16 bf16x4 __attribute__((ext_vector_type(4)));
typedef __bf16 bf16x8 __attribute__((ext_vector_type(8)));
typedef float  f32x4  __attribute__((ext_vector_type(4)));
typedef uint32_t u32x4 __attribute__((ext_vector_type(4)));

#define MFMA16(a, b, c) __builtin_amdgcn_mfma_f32_16x16x32_bf16(a, b, c, 0, 0, 0)

__device__ __forceinline__ void gload_lds16(const void* g, void* s) {
  __builtin_amdgcn_global_load_lds(
      (const __attribute__((address_space(1))) void*)g,
      (__attribute__((address_space(3))) void*)s, 16, 0, 0);
}

__device__ __forceinline__ uint32_t pkbf(float a, float b) {
  return __builtin_bit_cast(uint32_t, (bf16x2){(bf16)a, (bf16)b});
}

// raw v_exp_f32 (exp2); avoids the OCML correctly-rounded polynomial
__device__ __forceinline__ float fexp2(float x) {
  return __builtin_amdgcn_exp2f(x);
}

// ---------------------------------------------------------------------------
// 8 EE-sized f32->bf16 conversions in one launch: y<4 weights, y>=4 query 1/4s.
// ---------------------------------------------------------------------------
__global__ __launch_bounds__(256) void cvt8_bf16(const float* __restrict__ s0,
                                                 const float* __restrict__ s1,
                                                 const float* __restrict__ s2,
                                                 const float* __restrict__ s3,
                                                 const float* __restrict__ q,
                                                 bf16* __restrict__ d0,
                                                 bf16* __restrict__ d1,
                                                 bf16* __restrict__ d2,
                                                 bf16* __restrict__ d3,
                                                 bf16* __restrict__ dq,
                                                 long EE) {
  int y = blockIdx.y;
  const float* src;
  bf16* dst;
  if (y < 4) {
    src = y == 0 ? s0 : y == 1 ? s1 : y == 2 ? s2 : s3;
    dst = y == 0 ? d0 : y == 1 ? d1 : y == 2 ? d2 : d3;
  } else {
    src = q + (long)(y - 4) * EE;
    dst = dq + (long)(y - 4) * EE;
  }
  long i = ((long)blockIdx.x * 256 + threadIdx.x) * 4;
  f32x4 f = *(const f32x4*)(src + i);
  bf16x4 h = { (bf16)f.x, (bf16)f.y, (bf16)f.z, (bf16)f.w };
  *(bf16x4*)(dst + i) = h;
}

// ---------------------------------------------------------------------------
// Fused K+V gather through compacted idx, f32->bf16; skips rows >= cntp128.
// ---------------------------------------------------------------------------
__global__ __launch_bounds__(256) void gather2_cvt(const float* __restrict__ ks,
                                                   const float* __restrict__ vs,
                                                   bf16* __restrict__ kd,
                                                   bf16* __restrict__ vd,
                                                   const int* __restrict__ idx,
                                                   const int* __restrict__ cnts) {
  long i = (long)blockIdx.x * 256 + threadIdx.x;  // unit of 8 elements
  int row = (int)(i >> 8);
  int u = (int)(i & 255);
  int n = row >> 11, p = row & 2047;
  if (p >= cnts[4 + n]) return;                   // pad rows never consumed
  long srow = ((long)n << 11) + idx[(n << 11) + p];
  long so = srow * 2048 + u * 8;
  long dof = (long)row * 2048 + u * 8;
  {
    f32x4 a = *(const f32x4*)(ks + so);
    f32x4 b = *(const f32x4*)(ks + so + 4);
    bf16x8 h = { (bf16)a.x, (bf16)a.y, (bf16)a.z, (bf16)a.w,
                 (bf16)b.x, (bf16)b.y, (bf16)b.z, (bf16)b.w };
    *(bf16x8*)(kd + dof) = h;
  }
  {
    f32x4 a = *(const f32x4*)(vs + so);
    f32x4 b = *(const f32x4*)(vs + so + 4);
    bf16x8 h = { (bf16)a.x, (bf16)a.y, (bf16)a.z, (bf16)a.w,
                 (bf16)b.x, (bf16)b.y, (bf16)b.z, (bf16)b.w };
    *(bf16x8*)(vd + dof) = h;
  }
}

// ---------------------------------------------------------------------------
// Per-n compaction of mask==1 indices. grid = 4 x 256.
// ---------------------------------------------------------------------------
__global__ __launch_bounds__(256) void mask_compact(const int* __restrict__ mask,
                                                    int* __restrict__ idx,
                                                    int* __restrict__ cnts) {
  const int n = blockIdx.x;
  const int t = threadIdx.x, l = t & 63, w = t >> 6;
  const int* m = mask + n * 2048;
  __shared__ int wtot[4];
  int f[8], tt = 0;
  const int base = t * 8;
#pragma unroll
  for (int i = 0; i < 8; ++i) { f[i] = (m[base + i] != 0); tt += f[i]; }
  int sc = tt;
#pragma unroll
  for (int d = 1; d < 64; d <<= 1) {
    int v = __shfl_up(sc, d);
    if (l >= d) sc += v;
  }
  if (l == 63) wtot[w] = sc;
  __syncthreads();
  int woff = 0;
#pragma unroll
  for (int i = 0; i < 4; ++i) if (i < w) woff += wtot[i];
  int off = woff + sc - tt;
#pragma unroll
  for (int i = 0; i < 8; ++i)
    if (f[i]) { idx[n * 2048 + off] = base + i; ++off; }
  int total = wtot[0] + wtot[1] + wtot[2] + wtot[3];
  for (int p = total + t; p < 2048; p += 256) idx[n * 2048 + p] = 2047;
  if (t == 0) { cnts[n] = total; cnts[4 + n] = (total + 127) & ~127; }
}

// ---------------------------------------------------------------------------
// 256x256 GEMM, counted-vmcnt double-buffered pipeline (R9 verbatim —
// measured best: 196us QKV / ~96us outproj). QKV mode: blockIdx.z selects
// {Q: scale no-exit, K/V: exit no-scale} at runtime (uniform branches).
// ---------------------------------------------------------------------------
template <int QKV, int OUT_F32, int ADD_BIAS>
__global__ __launch_bounds__(512, 2) void gemm256(const bf16* __restrict__ A0,
                                                  const bf16* __restrict__ A1,
                                                  const bf16* __restrict__ A2,
                                                  const bf16* __restrict__ B0,
                                                  const bf16* __restrict__ B1,
                                                  const bf16* __restrict__ B2,
                                                  void* __restrict__ C0,
                                                  void* __restrict__ C1,
                                                  void* __restrict__ C2,
                                                  const float* __restrict__ bias,
                                                  const int* __restrict__ cnts) {
  constexpr int K = 2048, LDC = 2048, NT = 32;
  constexpr int TILE = 256 * 64;
  __shared__ bf16 S[2 * 2 * TILE];
  const int t = threadIdx.x;
  const int l = t & 63, w = t >> 6;
  const int wr = w >> 2, wc = w & 3;
  const int l15 = l & 15, l4 = l >> 4;

  const int z = blockIdx.z;
  const bf16* A = z == 0 ? A0 : z == 1 ? A1 : A2;
  const bf16* B = z == 0 ? B0 : z == 1 ? B1 : B2;
  void* Cout = z == 0 ? C0 : z == 1 ? C1 : C2;

  const int Mb = ((blockIdx.x & 7) << 2) + (blockIdx.x >> 3);
  const long tm = (long)Mb * 256;
  const long tn = (long)blockIdx.y * 256;

  if constexpr (QKV) {
    if (z) {  // K/V projections: skip blocks past compacted count
      int n = (int)(tm >> 11);
      if ((int)(tm & 2047) >= cnts[4 + n]) return;
    }
  }

  const bf16* Ab = A + tm * K;
  const bf16* Bb = B + tn * K;

  auto stage = [&](int T, int p) {
    bf16* sA = S + p * 2 * TILE;
    bf16* sB = sA + TILE;
    const bf16* Ak = Ab + T * 64;
    const bf16* Bk = Bb + T * 64;
#pragma unroll
    for (int i = 0; i < 4; ++i) {
      int u = i * 512 + t;
      int row = u >> 3, slot = u & 7;
      int ss = slot ^ (row & 7);
      gload_lds16(Ak + (long)row * K + ss * 8, sA + u * 8);
    }
#pragma unroll
    for (int i = 0; i < 4; ++i) {
      int u = i * 512 + t;
      int row = u >> 3, slot = u & 7;
      int ss = slot ^ (row & 7);
      gload_lds16(Bk + (long)row * K + ss * 8, sB + u * 8);
    }
  };

  f32x4 acc[8][4];
#pragma unroll
  for (int i = 0; i < 8; ++i)
#pragma unroll
    for (int j = 0; j < 4; ++j) acc[i][j] = (f32x4){0.f, 0.f, 0.f, 0.f};

  stage(0, 0);

  for (int T = 0; T < NT; ++T) {
    const int p = T & 1;
    const bf16* sA = S + p * 2 * TILE;
    const bf16* sB = sA + TILE;

    asm volatile("" ::: "memory");
    __builtin_amdgcn_s_barrier();
    asm volatile("" ::: "memory");
    if (T + 1 < NT) {
      stage(T + 1, p ^ 1);
      asm volatile("s_waitcnt vmcnt(8)" ::: "memory");
    } else {
      asm volatile("s_waitcnt vmcnt(0)" ::: "memory");
    }
    __builtin_amdgcn_s_barrier();
    asm volatile("" ::: "memory");

#pragma unroll
    for (int kk = 0; kk < 2; ++kk) {
      bf16x8 af[8], bf[4];
#pragma unroll
      for (int mi = 0; mi < 8; ++mi) {
        int row = wr * 128 + mi * 16 + l15;
        int slot = (kk * 4 + l4) ^ (row & 7);
        af[mi] = *(const bf16x8*)(sA + row * 64 + slot * 8);
      }
#pragma unroll
      for (int ni = 0; ni < 4; ++ni) {
        int row = wc * 64 + ni * 16 + l15;
        int slot = (kk * 4 + l4) ^ (row & 7);
        bf[ni] = *(const bf16x8*)(sB + row * 64 + slot * 8);
      }
      __builtin_amdgcn_s_setprio(1);
#pragma unroll
      for (int mi = 0; mi < 8; ++mi)
#pragma unroll
        for (int ni = 0; ni < 4; ++ni)
          acc[mi][ni] = MFMA16(af[mi], bf[ni], acc[mi][ni]);
      __builtin_amdgcn_s_setprio(0);
    }
  }

  // Q projection pre-scales logits into log2 domain (E^-0.5 * log2e)
  const float sc = (QKV && blockIdx.z == 0) ? 0.031879357f : 1.0f;
#pragma unroll
  for (int mi = 0; mi < 8; ++mi) {
#pragma unroll
    for (int ni = 0; ni < 4; ++ni) {
      long col = tn + wc * 64 + ni * 16 + l15;
      long row = tm + wr * 128 + mi * 16 + l4 * 4;
#pragma unroll
      for (int r = 0; r < 4; ++r) {
        float v = acc[mi][ni][r];
        if constexpr (QKV) v *= sc;
        if constexpr (OUT_F32) {
          if constexpr (ADD_BIAS) v += bias[col];
          ((float*)Cout)[(row + r) * (long)LDC + col] = v;
        } else {
          ((bf16*)Cout)[(row + r) * (long)LDC + col] = (bf16)v;
        }
      }
    }
  }
}

// ---------------------------------------------------------------------------
// Flash attention over COMPACTED keys. 1024 blocks x 512 threads (8 waves x
// 16 q-rows), XCD-swizzled decode. K/V SINGLE-buffered KVB=64 (32KB LDS);
// state fits 64 VGPR -> 8 waves/SIMD by natural allocation ((512,4) cap;
// R13: forcing 8 spilled; R15: KVB=128 spilled). Cross-block TLP hides
// staging latency. V mapping = R6 (coalesced + write-bank floor).
// Q pre-scaled (log2); native v_exp_f32; defer-max THR=11.5; T5 setprio.
// ---------------------------------------------------------------------------
__global__ __launch_bounds__(512, 4) void attn_fwd(const bf16* __restrict__ Qp,
                                                   const bf16* __restrict__ Kp,
                                                   const bf16* __restrict__ Vp,
                                                   const int* __restrict__ cnts,
                                                   bf16* __restrict__ Op) {
  constexpr int L = 2048, E = 2048, KVB = 64;
  __shared__ bf16 Kt[KVB * 128];      // [j][16 slots of 8], swizzled  16KB
  __shared__ bf16 VT[128 * KVB];      // [d][j], swizzled              16KB
  const int t = threadIdx.x, l = t & 63, w = t >> 6;
  const int l15 = l & 15, l4 = l >> 4;

  const int b = blockIdx.x;
  const int slot = ((b & 7) << 7) + (b >> 3);
  const int q0 = (slot & 15) << 7;
  const int y = slot >> 4;
  const int n = y >> 4, h = y & 15;
  const int wq = w * 16;

  const bf16* Qb = Qp + ((long)n * L + q0) * E + h * 128;
  const bf16* Kb = Kp + (long)n * L * E + h * 128;
  const bf16* Vb = Vp + (long)n * L * E + h * 128;
  const int cnt = cnts[n];
  const int ntk = (cnt + 63) >> 6;

  bf16x8 qf[4];
#pragma unroll
  for (int kk = 0; kk < 4; ++kk)
    qf[kk] = *(const bf16x8*)(Qb + (long)(wq + l15) * E + kk * 32 + l4 * 8);

  f32x4 o[8];
#pragma unroll
  for (int ni = 0; ni < 8; ++ni) o[ni] = (f32x4){0.f, 0.f, 0.f, 0.f};
  float mreg = -1e20f, lreg = 0.f;

  // V-transpose mapping (R6: coalesced global + write-bank floor)
  const int vj0 = ((l15 & 1) + 2 * l4 + 8 * (w & 1)) * 4;
  const int vd0 = ((l15 >> 1) + 8 * (w >> 1)) * 4;

  for (int ti = 0; ti < ntk; ++ti) {
    const int kv = ti << 6;

    // ---- stage K (async gload_lds) + V (reg transpose round-trip)
#pragma unroll
    for (int i = 0; i < 2; ++i) {
      int u = i * 512 + t;
      int row = u >> 4, sl = u & 15;
      gload_lds16(Kb + (long)(kv + row) * E + ((sl ^ (row & 7)) * 8),
                  &Kt[u * 8]);
    }
    bf16x4 vr[4];
#pragma unroll
    for (int r = 0; r < 4; ++r)
      vr[r] = *(const bf16x4*)(Vb + (long)(kv + vj0 + r) * E + vd0);
#pragma unroll
    for (int i = 0; i < 4; ++i) {
      int d = vd0 + i;
      bf16x4 pk = { vr[0][i], vr[1][i], vr[2][i], vr[3][i] };
      *(bf16x4*)(&VT[d * KVB + (vj0 ^ ((d & 7) << 3))]) = pk;
    }
    __syncthreads();   // drains vmcnt/lgkm: Kt + VT ready for all waves

    // ---- S^T = K Q^T  (rows j, cols q); S pre-scaled, log2 domain
    f32x4 s[4];
#pragma unroll
    for (int ni = 0; ni < 4; ++ni) s[ni] = (f32x4){0.f, 0.f, 0.f, 0.f};
#pragma unroll
    for (int kk = 0; kk < 4; ++kk) {
      bf16x8 kf[4];
#pragma unroll
      for (int ni = 0; ni < 4; ++ni) {
        int row = ni * 16 + l15;
        int sl = (kk * 4 + l4) ^ (row & 7);
        kf[ni] = *(const bf16x8*)(&Kt[row * 128 + sl * 8]);
      }
      __builtin_amdgcn_s_setprio(1);
#pragma unroll
      for (int ni = 0; ni < 4; ++ni)
        s[ni] = MFMA16(kf[ni], qf[kk], s[ni]);
      __builtin_amdgcn_s_setprio(0);
    }

    // ---- tail mask only (j >= cnt -> -1e20); non-tail tiles: nothing
    if (kv + KVB > cnt) {
#pragma unroll
      for (int ni = 0; ni < 4; ++ni)
#pragma unroll
        for (int r = 0; r < 4; ++r) {
          int j = kv + ni * 16 + l4 * 4 + r;
          s[ni][r] = (j < cnt) ? s[ni][r] : -1e20f;
        }
    }

    // ---- online softmax (exp2 domain, native v_exp); defer-max THR=11.5
    float m1 = fmaxf(fmaxf(s[0][0], s[0][1]), s[0][2]);
    float m2 = fmaxf(fmaxf(s[0][3], s[1][0]), s[1][1]);
    float m3 = fmaxf(fmaxf(s[1][2], s[1][3]), s[2][0]);
    float m4 = fmaxf(fmaxf(s[2][1], s[2][2]), s[2][3]);
    float m5 = fmaxf(fmaxf(s[3][0], s[3][1]), s[3][2]);
    float vmax = fmaxf(fmaxf(fmaxf(m1, m2), m3), fmaxf(fmaxf(m4, m5), s[3][3]));
    vmax = fmaxf(vmax, __shfl_xor(vmax, 16));
    vmax = fmaxf(vmax, __shfl_xor(vmax, 32));
    bool nd = vmax > mreg + 11.5f;
    float corr = nd ? fexp2(mreg - vmax) : 1.0f;
    float mn = nd ? vmax : mreg;
    mreg = mn;
    float rsum = 0.f;
    uint32_t u[4][2];
#pragma unroll
    for (int ni = 0; ni < 4; ++ni) {
      float p0 = fexp2(s[ni][0] - mn);
      float p1 = fexp2(s[ni][1] - mn);
      float p2 = fexp2(s[ni][2] - mn);
      float p3 = fexp2(s[ni][3] - mn);
      rsum += (p0 + p1) + (p2 + p3);
      u[ni][0] = pkbf(p0, p1);
      u[ni][1] = pkbf(p2, p3);
    }
    rsum += __shfl_xor(rsum, 16);
    rsum += __shfl_xor(rsum, 32);
    lreg = lreg * corr + rsum;
    if (__any(nd)) {               // rare: rescale o (rows q = wq + l4*4 + r)
#pragma unroll
      for (int r = 0; r < 4; ++r) {
        float cr = __shfl(corr, l4 * 20 + r);
#pragma unroll
        for (int ni = 0; ni < 8; ++ni) o[ni][r] *= cr;
      }
    }

    // ---- P redistribute (in-register) + PV
    const int srcA = l15 + ((l & 16) << 1);
    const int srcB = srcA + 16;
    const bool e5 = (l4 >> 1) != 0;
#pragma unroll
    for (int kk = 0; kk < 2; ++kk) {
      uint32_t a0 = (uint32_t)__shfl((int)u[kk * 2][0], srcA);
      uint32_t a1 = (uint32_t)__shfl((int)u[kk * 2][1], srcA);
      uint32_t a2 = (uint32_t)__shfl((int)u[kk * 2][0], srcB);
      uint32_t a3 = (uint32_t)__shfl((int)u[kk * 2][1], srcB);
      uint32_t b0 = (uint32_t)__shfl((int)u[kk * 2 + 1][0], srcA);
      uint32_t b1 = (uint32_t)__shfl((int)u[kk * 2 + 1][1], srcA);
      uint32_t b2 = (uint32_t)__shfl((int)u[kk * 2 + 1][0], srcB);
      uint32_t b3 = (uint32_t)__shfl((int)u[kk * 2 + 1][1], srcB);
      u32x4 pw = { e5 ? b0 : a0, e5 ? b1 : a1, e5 ? b2 : a2, e5 ? b3 : a3 };
      bf16x8 pa = __builtin_bit_cast(bf16x8, pw);
      bf16x8 vb[8];
#pragma unroll
      for (int ni = 0; ni < 8; ++ni) {
        int d = ni * 16 + l15;
        int col = (kk * 32 + l4 * 8) ^ ((d & 7) << 3);
        vb[ni] = *(const bf16x8*)(&VT[d * KVB + col]);
      }
      __builtin_amdgcn_s_setprio(1);
#pragma unroll
      for (int ni = 0; ni < 8; ++ni)
        o[ni] = MFMA16(pa, vb[ni], o[ni]);
      __builtin_amdgcn_s_setprio(0);
    }

    __syncthreads();   // all waves done reading Kt/VT before next overwrite
  }

  // ---- epilogue (rows q = wq + l4*4 + r; 1/l held at lane l15=q)
  float inv = 1.f / lreg;
#pragma unroll
  for (int r = 0; r < 4; ++r) {
    float iv = __shfl(inv, l4 * 20 + r);
    long grow = (long)n * L + q0 + wq + l4 * 4 + r;
#pragma unroll
    for (int ni = 0; ni < 8; ++ni)
      Op[grow * E + h * 128 + ni * 16 + l15] = (bf16)(o[ni][r] * iv);
  }
}

// ---------------------------------------------------------------------------
extern "C" void kernel_launch(void* const* d_in, const int* in_sizes, int n_in,
                              void* d_out, int out_size, void* d_ws, size_t ws_size,
                              hipStream_t stream) {
  (void)in_sizes; (void)n_in; (void)out_size; (void)ws_size;
  const float* query = (const float*)d_in[0];
  const float* keys  = (const float*)d_in[1];
  const float* values= (const float*)d_in[2];
  const int*   mask  = (const int*)d_in[3];
  const float* Wq = (const float*)d_in[4];
  const float* Wk = (const float*)d_in[5];
  const float* Wv = (const float*)d_in[6];
  const float* Wo = (const float*)d_in[7];
  const float* bo = (const float*)d_in[8];
  float* out = (float*)d_out;

  const int N = 4, L = 2048, E = 2048;
  const int M = N * L;  // 8192
  const long EE = (long)E * E;
  const long ME = (long)M * E;

  int*  idx  = (int*)d_ws;
  int*  cnts = idx + N * 2048;
  bf16* Wqb  = (bf16*)((char*)d_ws + 65536);
  bf16* Wkb  = Wqb + EE;
  bf16* Wvb  = Wkb + EE;
  bf16* Wob  = Wvb + EE;
  bf16* qp   = Wob + EE;
  bf16* kp   = qp + ME;    // query staging first, then K projection
  bf16* vp   = kp + ME;
  bf16* xq   = kp;                         // bf16 query staging (dead @ K-GEMM)
  bf16* xk   = (bf16*)d_out;               // gathered keys   (lo 32MB of d_out)
  bf16* xv   = (bf16*)d_out + ME;          // gathered values (hi 32MB of d_out)

  const int cbw = (int)(EE / 4 / 256);     // 4096
  const int gbl = (int)(ME / 8 / 256);     // 8192
  dim3 ggqkv(32, 8, 3);
  dim3 gg(32, 8, 1);

  mask_compact<<<4, 256, 0, stream>>>(mask, idx, cnts);
  cvt8_bf16<<<dim3(cbw, 8), 256, 0, stream>>>(Wq, Wk, Wv, Wo, query,
                                              Wqb, Wkb, Wvb, Wob, xq, EE);
  gather2_cvt<<<gbl, 256, 0, stream>>>(keys, values, xk, xv, idx, cnts);

  // Q+K+V projections in ONE launch (z=0: Q pre-scaled; z=1: K; z=2: V)
  gemm256<1, 0, 0><<<ggqkv, 512, 0, stream>>>(xq, xk, xv, Wqb, Wkb, Wvb,
                                              qp, kp, vp, nullptr, cnts);
  // attention over compacted keys (output aliases qp)
  attn_fwd<<<1024, 512, 0, stream>>>(qp, kp, vp, cnts, qp);
  // output projection + bias (overwrites all of d_out incl. xk/xv)
  gemm256<0, 1, 1><<<gg, 512, 0, stream>>>(qp, qp, qp, Wob, Wob, Wob,
                                           out, out, out, bo, cnts);
}